// Round 10
// baseline (348.198 us; speedup 1.0000x reference)
//
#include <hip/hip_runtime.h>
#include <math.h>

namespace {
constexpr int CDIM   = 128;
constexpr int KCODES = 1024;
constexpr int HWSZ   = 4096;   // 64*64
constexpr int BATCH  = 16;
constexpr int NPOS   = BATCH * HWSZ;            // 65536
constexpr int P      = 128;                     // positions per block
constexpr int TK     = 128;                     // codes per k-strip iteration
constexpr int NTILES = KCODES / TK;             // 8
constexpr int THREADS = 512;                    // 8 waves
constexpr size_t QELEMS   = (size_t)BATCH * CDIM * HWSZ;   // 8388608
constexpr size_t IDX_OFF  = QELEMS;                        // float32 elements
constexpr size_t LOSS_OFF = IDX_OFF + (size_t)NPOS;        // 8454144
constexpr size_t PERP_OFF = LOSS_OFF + 1;
// d_ws float-element offsets
constexpr int WS_C2   = 0;      // [0,1024)   float ||c_k||^2 (numpy-bit-exact)
constexpr int WS_HIST = 1024;   // [1024,2048) uint  usage counts
constexpr int WS_LOSS = 2048;   // [2048]     float sum ||z-q||^2
constexpr float INV_TOTAL = 1.0f / (float)QELEMS;
constexpr float INV_NPOS  = 1.0f / (float)NPOS;
}

// Bit-exact replica of numpy pairwise_sum for n=128 contiguous float32 applied
// to elementwise squares: 8 accumulator chains (stride 8), sequential within a
// chain, combined ((r0+r1)+(r2+r3))+((r4+r5)+(r6+r7)). __f*_rn forbids fma
// contraction (numpy multiplies into a temp, then adds — never fused).
__device__ __forceinline__ float np_sumsq_128(const float* v) {
    float r[8];
    #pragma unroll
    for (int j = 0; j < 8; ++j) r[j] = __fmul_rn(v[j], v[j]);
    #pragma unroll
    for (int i = 8; i < 128; i += 8) {
        #pragma unroll
        for (int j = 0; j < 8; ++j)
            r[j] = __fadd_rn(r[j], __fmul_rn(v[i + j], v[i + j]));
    }
    const float s01 = __fadd_rn(r[0], r[1]);
    const float s23 = __fadd_rn(r[2], r[3]);
    const float s45 = __fadd_rn(r[4], r[5]);
    const float s67 = __fadd_rn(r[6], r[7]);
    return __fadd_rn(__fadd_rn(s01, s23), __fadd_rn(s45, s67));
}

// ---- pass 0: codebook norms (numpy-bit-exact) + zero accumulators ----------
__global__ __launch_bounds__(256) void vq_prep(const float* __restrict__ cb,
                                               float* __restrict__ ws) {
    const int k = blockIdx.x * 256 + threadIdx.x;   // 0..1023
    const float* row = cb + (size_t)k * CDIM;
    float rr[CDIM];
    #pragma unroll
    for (int c = 0; c < CDIM; ++c) rr[c] = row[c];
    ws[WS_C2 + k] = np_sumsq_128(rr);
    ((unsigned int*)ws)[WS_HIST + k] = 0u;
    if (k == 0) ws[WS_LOSS] = 0.0f;
}

// ---- pass 1: register-blocked argmin, codes streamed from L2 ---------------
// Round 10. R9 (2 waves/SIMD, tile-in-LDS): 258us, VALUBusy 62%. Remaining
// stall: LDS pipe ~saturated (96 b128/chunk/CU at ~12cy each ~ VALU demand)
// + 14 staging barriers + only 2 waves/SIMD. Fix: drop the code-tile LDS path
// entirely. cv[j] reads go DIRECTLY to global: codebook is 512KB L2-resident,
// and each load instr touches only 2 distinct 16B lines per wave (cg=tid>>5)
// -> L1/L2 broadcast on the idle VMEM pipe. Gains: LDS insts/chunk/wave 12->4
// (z only, proven conflict-free); ZERO barriers in main loop (waves drift ->
// natural VMEM/LDS/VALU interleave); LDS 150->75KB -> 2 blocks/CU = 4 waves/
// SIMD (TLP hides ~200cy L2 latency). cg-pair combine via shfl_xor(32) halves
// the bdls/bkls arrays. Addressing: 8 loads/chunk with folded offset:j*512.
// launch_bounds(512,4) caps VGPR at 128 (est. ~107 live) — WRITE_SIZE is the
// spill tripwire (R4 lesson: 34MB good, 250MB = scratch catastrophe).
// Bit-exactness: per (pos,code) ONE ascending-c fma chain (c,c+1,c+2,c+3 in
// chunk, chunks ascend); z2 numpy pairwise 8-chain; d = fl(fl(z2-2zc)+c2);
// strict-< ascending-k; cross-subset lexicographic (d,k) min (shfl pair +
// 8-way LDS) == np.argmin first-index tie-break over disjoint subsets.
__global__ __launch_bounds__(512, 4) void vq_main(const float* __restrict__ z,
                                                  const float* __restrict__ cb,
                                                  float* __restrict__ ws,
                                                  float* __restrict__ out) {
    __shared__ __align__(16) float zt[CDIM][P];     // 64 KB  zt[c][p]
    __shared__ float z2s[P];                        // 512 B
    __shared__ float bdls[8][P];                    // 4 KB  per-cg-pair best_d
    __shared__ int   bkls[8][P];                    // 4 KB  per-cg-pair best_k
    __shared__ int   wkls[P];                       // 512 B winning code
    __shared__ float red[THREADS];                  // 2 KB   (total ~75 KB)

    const int tid   = threadIdx.x;
    const int nbase = blockIdx.x * P;
    const int b     = nbase >> 12;          // 4096 positions per batch image
    const int hw0   = nbase & (HWSZ - 1);   // 128-aligned
    const float* zb = z + (size_t)b * CDIM * HWSZ + hw0;

    // ---- stage z strip: zt[c][p] = z[b][c][hw0+p] (coalesced) --------------
    #pragma unroll
    for (int i = 0; i < (CDIM * P / 4) / THREADS; ++i) {   // 8 iters
        const int linear = i * THREADS + tid;              // 0..4095
        const int c  = linear >> 5;                        // 32 float4 per row
        const int p4 = (linear & 31) * 4;
        *(float4*)&zt[c][p4] = *(const float4*)(zb + (size_t)c * HWSZ + p4);
    }
    __syncthreads();

    // ---- z2 per position: numpy pairwise 8-chain, streamed from LDS --------
    if (tid < P) {
        const int p = tid;
        float r[8];
        #pragma unroll
        for (int j = 0; j < 8; ++j) {
            const float x = zt[j][p];
            r[j] = __fmul_rn(x, x);
        }
        #pragma unroll
        for (int i = 8; i < CDIM; i += 8) {
            #pragma unroll
            for (int j = 0; j < 8; ++j) {
                const float x = zt[i + j][p];
                r[j] = __fadd_rn(r[j], __fmul_rn(x, x));
            }
        }
        const float s01 = __fadd_rn(r[0], r[1]);
        const float s23 = __fadd_rn(r[2], r[3]);
        const float s45 = __fadd_rn(r[4], r[5]);
        const float s67 = __fadd_rn(r[6], r[7]);
        z2s[p] = __fadd_rn(__fadd_rn(s01, s23), __fadd_rn(s45, s67));
    }
    __syncthreads();

    const int pg = tid & 31;      // position group: p0..p0+3  (32 groups)
    const int cg = tid >> 5;      // code group 0..15: codes k0..k0+7 per strip
    const int p0 = pg * 4;
    const int k0 = cg * 8;
    const float* c2g = ws + WS_C2;
    const float4* cb4 = (const float4*)cb;   // 32 float4 per codebook row

    float z2r[4];
    #pragma unroll
    for (int i = 0; i < 4; ++i) z2r[i] = z2s[p0 + i];

    float bestd[4] = {INFINITY, INFINITY, INFINITY, INFINITY};
    int   bestk[4] = {0, 0, 0, 0};

    // ---- main loop: NO barriers; codes streamed from L2 --------------------
    for (int t = 0; t < NTILES; ++t) {
        const int kb = t * TK + k0;
        const float4* crow = cb4 + (size_t)kb * 32;

        float a[4][8];
        #pragma unroll
        for (int i = 0; i < 4; ++i)
            #pragma unroll
            for (int j = 0; j < 8; ++j) a[i][j] = 0.0f;

        // 32 independent fma chains, each ascending c (reference order).
        // Per chunk: 4 ds_read_b128 (z, 2-way bcast = free) + 8 VMEM dwordx4
        // (2 distinct L2-hot lines/wave) + 128 FMA.
        for (int c4 = 0; c4 < CDIM / 4; ++c4) {
            const int c = c4 * 4;
            const float4 zv0 = *(const float4*)&zt[c + 0][p0];
            const float4 zv1 = *(const float4*)&zt[c + 1][p0];
            const float4 zv2 = *(const float4*)&zt[c + 2][p0];
            const float4 zv3 = *(const float4*)&zt[c + 3][p0];
            float4 cv[8];
            #pragma unroll
            for (int j = 0; j < 8; ++j) cv[j] = crow[(size_t)j * 32 + c4];
            #pragma unroll
            for (int j = 0; j < 8; ++j) {
                a[0][j] = fmaf(zv0.x, cv[j].x, a[0][j]);
                a[0][j] = fmaf(zv1.x, cv[j].y, a[0][j]);
                a[0][j] = fmaf(zv2.x, cv[j].z, a[0][j]);
                a[0][j] = fmaf(zv3.x, cv[j].w, a[0][j]);
                a[1][j] = fmaf(zv0.y, cv[j].x, a[1][j]);
                a[1][j] = fmaf(zv1.y, cv[j].y, a[1][j]);
                a[1][j] = fmaf(zv2.y, cv[j].z, a[1][j]);
                a[1][j] = fmaf(zv3.y, cv[j].w, a[1][j]);
                a[2][j] = fmaf(zv0.z, cv[j].x, a[2][j]);
                a[2][j] = fmaf(zv1.z, cv[j].y, a[2][j]);
                a[2][j] = fmaf(zv2.z, cv[j].z, a[2][j]);
                a[2][j] = fmaf(zv3.z, cv[j].w, a[2][j]);
                a[3][j] = fmaf(zv0.w, cv[j].x, a[3][j]);
                a[3][j] = fmaf(zv1.w, cv[j].y, a[3][j]);
                a[3][j] = fmaf(zv2.w, cv[j].z, a[3][j]);
                a[3][j] = fmaf(zv3.w, cv[j].w, a[3][j]);
            }
        }

        // d = fl(fl(z2 - 2*zc) + c2); strict < with ascending k (t, then j)
        #pragma unroll
        for (int j = 0; j < 8; ++j) {
            const float c2 = c2g[kb + j];
            #pragma unroll
            for (int i = 0; i < 4; ++i) {
                const float d = __fadd_rn(fmaf(-2.0f, a[i][j], z2r[i]), c2);
                if (d < bestd[i]) { bestd[i] = d; bestk[i] = kb + j; }
            }
        }
    }

    // ---- combine cg pairs (cg, cg^1) in-wave via shfl_xor(32) --------------
    #pragma unroll
    for (int i = 0; i < 4; ++i) {
        const float od = __shfl_xor(bestd[i], 32);
        const int   ok = __shfl_xor(bestk[i], 32);
        if (od < bestd[i] || (od == bestd[i] && ok < bestk[i])) {
            bestd[i] = od; bestk[i] = ok;
        }
    }
    if ((tid & 32) == 0) {
        #pragma unroll
        for (int i = 0; i < 4; ++i) {
            bdls[cg >> 1][p0 + i] = bestd[i];
            bkls[cg >> 1][p0 + i] = bestk[i];
        }
    }
    __syncthreads();

    // ---- combine 8 disjoint code-subsets per position; lexicographic (d,k)
    unsigned int* ghist = (unsigned int*)ws + WS_HIST;
    if (tid < P) {
        const int p = tid;
        float bd = bdls[0][p];
        int   bk = bkls[0][p];
        #pragma unroll
        for (int g = 1; g < 8; ++g) {
            const float d = bdls[g][p];
            const int   k = bkls[g][p];
            if (d < bd || (d == bd && k < bk)) { bd = d; bk = k; }
        }
        wkls[p] = bk;
        out[IDX_OFF + (size_t)(nbase + p)] = (float)bk;
        atomicAdd(&ghist[bk], 1u);       // 128/block, 1024 bins: low contention
        red[tid] = bd;     // best_d == fl(||z-q||^2), loss has 2% slack
    } else {
        red[tid] = 0.0f;
    }
    __syncthreads();
    for (int s = THREADS / 2; s > 0; s >>= 1) {
        if (tid < s) red[tid] += red[tid + s];
        __syncthreads();
    }
    if (tid == 0) atomicAdd(&ws[WS_LOSS], red[0]);

    // ---- quantized output: out[b][c][hw0+p] = cb[wk[p]][c] -----------------
    // stores coalesced (512B per c-row); cb gather L1/L2-hot.
    float* ob = out + (size_t)b * CDIM * HWSZ + hw0;
    #pragma unroll
    for (int i = 0; i < (CDIM * P) / THREADS; ++i) {   // 32 iters
        const int linear = i * THREADS + tid;          // 0..16383
        const int c = linear >> 7;
        const int p = linear & 127;
        ob[(size_t)c * HWSZ + p] = cb[(size_t)wkls[p] * CDIM + c];
    }
}

// ---- pass 2: scalars --------------------------------------------------------
__global__ __launch_bounds__(1024) void vq_final(const float* __restrict__ ws,
                                                 float* __restrict__ out) {
    __shared__ float red[1024];
    const int t = threadIdx.x;
    const unsigned int* hist = (const unsigned int*)ws + WS_HIST;
    const float p = (float)hist[t] * INV_NPOS;
    red[t] = p * logf(p + 1e-10f);
    __syncthreads();
    for (int s = 512; s > 0; s >>= 1) {
        if (t < s) red[t] += red[t + s];
        __syncthreads();
    }
    if (t == 0) {
        out[LOSS_OFF] = 1.25f * (ws[WS_LOSS] * INV_TOTAL);   // cb + 0.25*commit
        out[PERP_OFF] = expf(-red[0]);
    }
}

extern "C" void kernel_launch(void* const* d_in, const int* in_sizes, int n_in,
                              void* d_out, int out_size, void* d_ws, size_t ws_size,
                              hipStream_t stream) {
    const float* z  = (const float*)d_in[0];
    const float* cb = (const float*)d_in[1];
    float* out = (float*)d_out;
    float* ws  = (float*)d_ws;

    vq_prep <<<KCODES / 256, 256, 0, stream>>>(cb, ws);
    vq_main <<<NPOS / P,     THREADS, 0, stream>>>(z, cb, ws, out);
    vq_final<<<1,           1024, 0, stream>>>(ws, out);
}